// Round 4
// baseline (578.601 us; speedup 1.0000x reference)
//
#include <hip/hip_runtime.h>
#include <stdint.h>

#define B_ 8
#define S_ 1024
#define D_ 1024
#define H_ 2048
#define E_ 8
#define DN_ 256

typedef unsigned short u16;
typedef __bf16 bf16x8 __attribute__((ext_vector_type(8)));
typedef float f32x4 __attribute__((ext_vector_type(4)));

__device__ __forceinline__ u16 f2b(float f) {
  uint32_t u = __float_as_uint(f);
  u += 0x7fffu + ((u >> 16) & 1u);
  return (u16)(u >> 16);
}

// async global->LDS, 16B per lane. LDS dest is wave-uniform base; HW adds lane*16.
__device__ __forceinline__ void gll16(const void* g, void* l) {
  __builtin_amdgcn_global_load_lds(
      (__attribute__((address_space(1))) void*)g,
      (__attribute__((address_space(3))) void*)l, 16, 0, 0);
}

// ---------------- router ----------------
__global__ void router_kernel(const float* __restrict__ noise,
                              const float* __restrict__ rw,
                              float* __restrict__ out_logits,
                              float* __restrict__ out_probs,
                              float* __restrict__ out_idx,
                              float* __restrict__ out_w,
                              int* __restrict__ ws_idx,
                              float* __restrict__ ws_w) {
  __shared__ float sl[64];
  __shared__ float sp[64];
  const int t = threadIdx.x;           // 64 threads
  const int b = t >> 3, e = t & 7;
  float acc = 0.f;
  for (int d = 0; d < DN_; ++d) acc += noise[b * DN_ + d] * rw[d * E_ + e];
  sl[t] = acc;
  out_logits[t] = acc;
  __syncthreads();
  float m = -1e30f;
  for (int j = 0; j < 8; ++j) m = fmaxf(m, sl[b * 8 + j]);
  float s = 0.f;
  for (int j = 0; j < 8; ++j) s += __expf(sl[b * 8 + j] - m);
  const float p = __expf(acc - m) / s;
  out_probs[t] = p;
  sp[t] = p;
  __syncthreads();
  if (e == 0) {
    int a1 = 0; float v1 = sp[b * 8];
    for (int j = 1; j < 8; ++j) { float v = sp[b * 8 + j]; if (v > v1) { v1 = v; a1 = j; } }
    int a2 = -1; float v2 = -1e30f;
    for (int j = 0; j < 8; ++j) {
      if (j == a1) continue;
      float v = sp[b * 8 + j]; if (v > v2) { v2 = v; a2 = j; }
    }
    float sum = fmaxf(v1 + v2, 1e-8f);
    float w1 = v1 / sum, w2 = v2 / sum;
    out_idx[b * 2] = (float)a1; out_idx[b * 2 + 1] = (float)a2;
    out_w[b * 2] = w1; out_w[b * 2 + 1] = w2;
    ws_idx[b * 2] = a1; ws_idx[b * 2 + 1] = a2;
    ws_w[b * 2] = w1; ws_w[b * 2 + 1] = w2;
  }
}

// ---------------- cast x -> bf16 ----------------
__global__ void cast_x_kernel(const float* __restrict__ x, u16* __restrict__ xb) {
  const size_t i = ((size_t)blockIdx.x * blockDim.x + threadIdx.x) * 4;
  float4 v = *(const float4*)(x + i);
  ushort4 o; o.x = f2b(v.x); o.y = f2b(v.y); o.z = f2b(v.z); o.w = f2b(v.w);
  *(ushort4*)(xb + i) = o;
}

// ---------------- add partial: out += part ----------------
__global__ void add_kernel(float4* __restrict__ out, const float4* __restrict__ part) {
  const size_t i = (size_t)blockIdx.x * blockDim.x + threadIdx.x;
  float4 a = out[i], b = part[i];
  a.x += b.x; a.y += b.y; a.z += b.z; a.w += b.w;
  out[i] = a;
}

// ---------------- transpose + cast: f32 [R][C] per expert -> bf16 [C][R] ----------------
template <int R, int C>
__global__ void transpose_cast_kernel(const float* __restrict__ in, u16* __restrict__ out) {
  __shared__ u16 tile[64][68];   // [c_local][r_local], stride 68
  const int e = blockIdx.z;
  const float* ip = in + (size_t)e * R * C;
  u16* op = out + (size_t)e * R * C;
  const int r0 = blockIdx.y * 64, c0 = blockIdx.x * 64;
  const int t = threadIdx.x;
  const int rr = t >> 4;        // 0..15
  const int c4 = t & 15;        // 0..15 (group of 4 cols)
#pragma unroll
  for (int i = 0; i < 4; ++i) {
    const int r = rr + i * 16;
    float4 v = *(const float4*)(ip + (size_t)(r0 + r) * C + c0 + c4 * 4);
    tile[c4 * 4 + 0][r] = f2b(v.x);
    tile[c4 * 4 + 1][r] = f2b(v.y);
    tile[c4 * 4 + 2][r] = f2b(v.z);
    tile[c4 * 4 + 3][r] = f2b(v.w);
  }
  __syncthreads();
#pragma unroll
  for (int i = 0; i < 4; ++i) {
    const int c = rr + i * 16;
    ushort4 v;
    v.x = tile[c][c4 * 4 + 0];
    v.y = tile[c][c4 * 4 + 1];
    v.z = tile[c][c4 * 4 + 2];
    v.w = tile[c][c4 * 4 + 3];
    *(ushort4*)(op + (size_t)(c0 + c) * R + r0 + c4 * 4) = v;
  }
}

// ---------------- GEMM1: hidden = silu-gated(x @ W_in + b_in) * coeff ----------------
// Block tile: 128 s-rows x 64 hid-cols (value half + gate half share one B-tile).
// XOR-swizzled LDS: LDS[r][c] holds global k-chunk c ^ ((r>>1)&3)  -> conflict-free b128 reads.
__global__ void __launch_bounds__(256, 4) gemm1_kernel(
    const u16* __restrict__ xb,     // [B][S][D] bf16
    const u16* __restrict__ wtin,   // [E][2H][D] bf16 (pre-transposed)
    const float* __restrict__ bin,  // [E][2H] f32
    const int* __restrict__ ws_idx, const float* __restrict__ ws_w,
    u16* __restrict__ hid)          // [B*2][S][H] bf16
{
  const int nt = blockIdx.x;   // 32 tiles of 64 hid-cols
  const int mt = blockIdx.y;   // 8 s-tiles
  const int z  = blockIdx.z;   // 16 = b*2+slot
  const int b  = z >> 1;
  const int e  = ws_idx[z] & 7;
  const float csc = ws_w[z];

  __shared__ u16 As[128 * 32];
  __shared__ u16 Bs[128 * 32];   // rows 0-63: value cols, rows 64-127: gate cols

  const int t = threadIdx.x;
  const int wave = t >> 6, lane = t & 63;
  const int wm = wave >> 1, wn = wave & 1;
  const int lm = lane & 15, lq = lane >> 4;
  const int lrow = lane >> 2;
  const int kg = (lane & 3) ^ ((lane >> 3) & 3);   // swizzled global k-chunk
  const int lk = kg * 8;
  const int sw = (lm >> 1) & 3;                    // fragment-read chunk swizzle

  const u16* Ab  = xb + (size_t)b * (S_ * D_) + (size_t)mt * 128 * D_;
  const u16* Bvb = wtin + (size_t)e * (2 * H_ * D_) + (size_t)nt * 64 * D_;
  const u16* Bgb = Bvb + (size_t)H_ * D_;

  const f32x4 vz = {0.f, 0.f, 0.f, 0.f};
  f32x4 accv[4][2], accg[4][2];
#pragma unroll
  for (int i = 0; i < 4; ++i)
#pragma unroll
    for (int j = 0; j < 2; ++j) { accv[i][j] = vz; accg[i][j] = vz; }

  for (int kt = 0; kt < D_ / 32; ++kt) {
    const int k0 = kt * 32 + lk;
    gll16(Ab + (size_t)(wave * 16 + lrow) * D_ + k0, (char*)As + wave * 1024);
    gll16(Ab + (size_t)((wave + 4) * 16 + lrow) * D_ + k0, (char*)As + (wave + 4) * 1024);
    gll16(Bvb + (size_t)(wave * 16 + lrow) * D_ + k0, (char*)Bs + wave * 1024);
    gll16(Bgb + (size_t)(wave * 16 + lrow) * D_ + k0, (char*)Bs + (wave + 4) * 1024);
    __syncthreads();
    bf16x8 af[4], bvf[2], bgf[2];
#pragma unroll
    for (int i = 0; i < 4; ++i)
      af[i] = *(const bf16x8*)(As + (wm * 64 + i * 16 + lm) * 32 + (lq ^ sw) * 8);
#pragma unroll
    for (int j = 0; j < 2; ++j) {
      bvf[j] = *(const bf16x8*)(Bs + (wn * 32 + j * 16 + lm) * 32 + (lq ^ sw) * 8);
      bgf[j] = *(const bf16x8*)(Bs + (64 + wn * 32 + j * 16 + lm) * 32 + (lq ^ sw) * 8);
    }
#pragma unroll
    for (int i = 0; i < 4; ++i)
#pragma unroll
      for (int j = 0; j < 2; ++j) {
        accv[i][j] = __builtin_amdgcn_mfma_f32_16x16x32_bf16(af[i], bvf[j], accv[i][j], 0, 0, 0);
        accg[i][j] = __builtin_amdgcn_mfma_f32_16x16x32_bf16(af[i], bgf[j], accg[i][j], 0, 0, 0);
      }
    __syncthreads();
  }

  u16* hb = hid + (size_t)z * (S_ * H_);
  const int row0 = mt * 128 + wm * 64;
  const int col0 = nt * 64 + wn * 32;
#pragma unroll
  for (int j = 0; j < 2; ++j) {
    const int col = col0 + j * 16 + lm;
    const float bvx = bin[e * 2 * H_ + col];
    const float bgx = bin[e * 2 * H_ + H_ + col];
#pragma unroll
    for (int i = 0; i < 4; ++i) {
#pragma unroll
      for (int r = 0; r < 4; ++r) {
        const int srow = row0 + i * 16 + lq * 4 + r;
        float v = accv[i][j][r] + bvx;
        float g = accg[i][j][r] + bgx;
        float hv = v * g / (1.f + __expf(-g)) * csc;   // value * silu(gate) * coeff
        hb[(size_t)srow * H_ + col] = f2b(hv);
      }
    }
  }
}

// ---------------- GEMM2 (split-K over slots): one slot's hidden @ W_out ----------------
// slot 0 -> out (+ full coeff-weighted bias); slot 1 -> f32 partial (added later).
__global__ void __launch_bounds__(256, 4) gemm2_kernel(
    const u16* __restrict__ hid,    // [B*2][S][H] bf16 (coeff pre-applied)
    const u16* __restrict__ wtout,  // [E][D][H] bf16 (pre-transposed)
    const float* __restrict__ bout, // [E][D] f32
    const int* __restrict__ ws_idx, const float* __restrict__ ws_w,
    float* __restrict__ out,        // [B][S][D] f32
    float* __restrict__ part)       // [B][S][D] f32 partial (slot 1)
{
  const int nt = blockIdx.x;  // 8 d-tiles
  const int mt = blockIdx.y;  // 8 s-tiles
  const int z  = blockIdx.z;  // 16 = b*2+slot
  const int b  = z >> 1, slot = z & 1;
  const int e  = ws_idx[z] & 7;

  __shared__ u16 As[128 * 32];
  __shared__ u16 Bs[128 * 32];

  const int t = threadIdx.x;
  const int wave = t >> 6, lane = t & 63;
  const int wm = wave >> 1, wn = wave & 1;
  const int lm = lane & 15, lq = lane >> 4;
  const int lrow = lane >> 2;
  const int kg = (lane & 3) ^ ((lane >> 3) & 3);
  const int lk = kg * 8;
  const int sw = (lm >> 1) & 3;

  const u16* Ab = hid + ((size_t)z * S_ + mt * 128) * H_;
  const u16* Bb = wtout + ((size_t)e * D_ + nt * 128) * H_;

  const f32x4 vz = {0.f, 0.f, 0.f, 0.f};
  f32x4 acc[4][4];
#pragma unroll
  for (int i = 0; i < 4; ++i)
#pragma unroll
    for (int j = 0; j < 4; ++j) acc[i][j] = vz;

  for (int kt = 0; kt < H_ / 32; ++kt) {
    const int k0 = kt * 32 + lk;
#pragma unroll
    for (int r = 0; r < 2; ++r) {
      const int ch = wave + r * 4;
      const int row = ch * 16 + lrow;
      gll16(Ab + (size_t)row * H_ + k0, (char*)As + ch * 1024);
      gll16(Bb + (size_t)row * H_ + k0, (char*)Bs + ch * 1024);
    }
    __syncthreads();
    bf16x8 af[4], bf[4];
#pragma unroll
    for (int i = 0; i < 4; ++i)
      af[i] = *(const bf16x8*)(As + (wm * 64 + i * 16 + lm) * 32 + (lq ^ sw) * 8);
#pragma unroll
    for (int j = 0; j < 4; ++j)
      bf[j] = *(const bf16x8*)(Bs + (wn * 64 + j * 16 + lm) * 32 + (lq ^ sw) * 8);
#pragma unroll
    for (int i = 0; i < 4; ++i)
#pragma unroll
      for (int j = 0; j < 4; ++j)
        acc[i][j] = __builtin_amdgcn_mfma_f32_16x16x32_bf16(af[i], bf[j], acc[i][j], 0, 0, 0);
    __syncthreads();
  }

  const int e0 = ws_idx[b * 2] & 7, e1 = ws_idx[b * 2 + 1] & 7;
  const float c0 = ws_w[b * 2], c1 = ws_w[b * 2 + 1];
  float* dst = (slot == 0 ? out : part) + (size_t)b * (S_ * D_);
  const int row0 = mt * 128 + wm * 64;
  const int col0 = nt * 128 + wn * 64;
#pragma unroll
  for (int j = 0; j < 4; ++j) {
    const int col = col0 + j * 16 + lm;
    const float bias = (slot == 0) ? (c0 * bout[e0 * D_ + col] + c1 * bout[e1 * D_ + col]) : 0.f;
#pragma unroll
    for (int i = 0; i < 4; ++i)
#pragma unroll
      for (int r = 0; r < 4; ++r)
        dst[(size_t)(row0 + i * 16 + lq * 4 + r) * D_ + col] = acc[i][j][r] + bias;
  }
}

extern "C" void kernel_launch(void* const* d_in, const int* in_sizes, int n_in,
                              void* d_out, int out_size, void* d_ws, size_t ws_size,
                              hipStream_t stream) {
  const float* x     = (const float*)d_in[0];
  const float* noise = (const float*)d_in[1];
  const float* rw    = (const float*)d_in[2];
  const float* fiw   = (const float*)d_in[3];
  const float* fib   = (const float*)d_in[4];
  const float* fow   = (const float*)d_in[5];
  const float* fob   = (const float*)d_in[6];
  float* out = (float*)d_out;

  char* ws = (char*)d_ws;
  int*   ws_idx = (int*)ws;                                 // 16 ints
  float* ws_w   = (float*)(ws + 64);                        // 16 floats
  u16* xb    = (u16*)(ws + 256);                            // [B][S][D] bf16
  u16* wtin  = xb + (size_t)B_ * S_ * D_;                   // [E][2H][D] bf16
  u16* wtout = wtin + (size_t)E_ * 2 * H_ * D_;             // [E][D][H] bf16
  u16* hid   = wtout + (size_t)E_ * D_ * H_;                // [B*2][S][H] bf16
  // part aliases wtin: gemm1 (last reader of wtin) completes before gemm2 writes it.
  float* part = (float*)wtin;                               // [B][S][D] f32 (32 MB)

  float* out_mixed  = out;
  float* out_logits = out + (size_t)B_ * S_ * D_;
  float* out_probs  = out_logits + B_ * E_;
  float* out_idx    = out_probs + B_ * E_;
  float* out_w      = out_idx + B_ * 2;

  router_kernel<<<1, 64, 0, stream>>>(noise, rw, out_logits, out_probs,
                                      out_idx, out_w, ws_idx, ws_w);
  cast_x_kernel<<<(B_ * S_ * D_ / 4) / 256, 256, 0, stream>>>(x, xb);
  transpose_cast_kernel<D_, 2 * H_><<<dim3((2 * H_) / 64, D_ / 64, E_), 256, 0, stream>>>(fiw, wtin);
  transpose_cast_kernel<H_, D_><<<dim3(D_ / 64, H_ / 64, E_), 256, 0, stream>>>(fow, wtout);
  gemm1_kernel<<<dim3(32, 8, 16), 256, 0, stream>>>(xb, wtin, fib, ws_idx, ws_w, hid);
  gemm2_kernel<<<dim3(8, 8, 16), 256, 0, stream>>>(hid, wtout, fob, ws_idx, ws_w, out_mixed, part);
  add_kernel<<<(B_ * S_ * D_ / 4) / 256, 256, 0, stream>>>((float4*)out_mixed, (const float4*)part);
}

// Round 5
// 455.278 us; speedup vs baseline: 1.2709x; 1.2709x over previous
//
#include <hip/hip_runtime.h>
#include <stdint.h>

#define B_ 8
#define S_ 1024
#define D_ 1024
#define H_ 2048
#define E_ 8
#define DN_ 256

typedef unsigned char u8;
typedef float f32x4 __attribute__((ext_vector_type(4)));
typedef long long ll;

// fp8 e4m3 (OCP on gfx950) converts
__device__ __forceinline__ u8 f2f8(float f) {
  return (u8)(__builtin_amdgcn_cvt_pk_fp8_f32(f, f, 0, false) & 0xff);
}
__device__ __forceinline__ unsigned int pk4f8(float a, float b, float c, float d) {
  int w = __builtin_amdgcn_cvt_pk_fp8_f32(a, b, 0, false);
  w = __builtin_amdgcn_cvt_pk_fp8_f32(c, d, w, true);
  return (unsigned int)w;
}

// async global->LDS, 16B per lane. LDS dest is wave-uniform base; HW adds lane*16.
__device__ __forceinline__ void gll16(const void* g, void* l) {
  __builtin_amdgcn_global_load_lds(
      (__attribute__((address_space(1))) void*)g,
      (__attribute__((address_space(3))) void*)l, 16, 0, 0);
}

// swizzle value for tile row r (16B-pair XOR): 2-way-max bank conflicts on b64 frag reads
__device__ __forceinline__ int swz(int r) { return (r & 3) ^ ((r >> 2) & 1); }

// ---------------- router ----------------
__global__ void router_kernel(const float* __restrict__ noise,
                              const float* __restrict__ rw,
                              float* __restrict__ out_logits,
                              float* __restrict__ out_probs,
                              float* __restrict__ out_idx,
                              float* __restrict__ out_w,
                              int* __restrict__ ws_idx,
                              float* __restrict__ ws_w) {
  __shared__ float sl[64];
  __shared__ float sp[64];
  const int t = threadIdx.x;           // 64 threads
  const int b = t >> 3, e = t & 7;
  float acc = 0.f;
  for (int d = 0; d < DN_; ++d) acc += noise[b * DN_ + d] * rw[d * E_ + e];
  sl[t] = acc;
  out_logits[t] = acc;
  __syncthreads();
  float m = -1e30f;
  for (int j = 0; j < 8; ++j) m = fmaxf(m, sl[b * 8 + j]);
  float s = 0.f;
  for (int j = 0; j < 8; ++j) s += __expf(sl[b * 8 + j] - m);
  const float p = __expf(acc - m) / s;
  out_probs[t] = p;
  sp[t] = p;
  __syncthreads();
  if (e == 0) {
    int a1 = 0; float v1 = sp[b * 8];
    for (int j = 1; j < 8; ++j) { float v = sp[b * 8 + j]; if (v > v1) { v1 = v; a1 = j; } }
    int a2 = -1; float v2 = -1e30f;
    for (int j = 0; j < 8; ++j) {
      if (j == a1) continue;
      float v = sp[b * 8 + j]; if (v > v2) { v2 = v; a2 = j; }
    }
    float sum = fmaxf(v1 + v2, 1e-8f);
    float w1 = v1 / sum, w2 = v2 / sum;
    out_idx[b * 2] = (float)a1; out_idx[b * 2 + 1] = (float)a2;
    out_w[b * 2] = w1; out_w[b * 2 + 1] = w2;
    ws_idx[b * 2] = a1; ws_idx[b * 2 + 1] = a2;
    ws_w[b * 2] = w1; ws_w[b * 2 + 1] = w2;
  }
}

// ---------------- cast x -> fp8 ----------------
__global__ void cast_x_kernel(const float* __restrict__ x, unsigned int* __restrict__ xq) {
  const size_t i = (size_t)blockIdx.x * blockDim.x + threadIdx.x;
  float4 v = *(const float4*)(x + i * 4);
  xq[i] = pk4f8(v.x, v.y, v.z, v.w);
}

// ---------------- transpose + cast: f32 [R][C] per expert -> fp8 [C][R] ----------------
template <int R, int C>
__global__ void transpose_cast_kernel(const float* __restrict__ in, u8* __restrict__ out) {
  __shared__ u8 tile[64][72];
  const int e = blockIdx.z;
  const float* ip = in + (size_t)e * R * C;
  u8* op = out + (size_t)e * R * C;
  const int r0 = blockIdx.y * 64, c0 = blockIdx.x * 64;
  const int t = threadIdx.x;
  const int rr = t >> 4;        // 0..15
  const int c4 = t & 15;        // 0..15 (group of 4 cols)
#pragma unroll
  for (int i = 0; i < 4; ++i) {
    const int r = rr + i * 16;
    float4 v = *(const float4*)(ip + (size_t)(r0 + r) * C + c0 + c4 * 4);
    tile[c4 * 4 + 0][r] = f2f8(v.x);
    tile[c4 * 4 + 1][r] = f2f8(v.y);
    tile[c4 * 4 + 2][r] = f2f8(v.z);
    tile[c4 * 4 + 3][r] = f2f8(v.w);
  }
  __syncthreads();
#pragma unroll
  for (int i = 0; i < 4; ++i) {
    const int c = rr + i * 16;
    unsigned int w = *(const unsigned int*)&tile[c][c4 * 4];
    *(unsigned int*)(op + (size_t)(c0 + c) * R + r0 + c4 * 4) = w;
  }
}

// ---------------- GEMM1: hidden = silu-gated(x @ W_in + b_in) * coeff  (fp8, BK=64) ----
// Block tile: 128 s-rows x 64 hid-cols (value + gate share one B-tile).
// LDS rows are 64 B (64 fp8 k-elems); 16B pairs XOR-swizzled by swz(row).
__global__ void __launch_bounds__(256, 4) gemm1_kernel(
    const u8* __restrict__ xq,      // [B][S][D] fp8
    const u8* __restrict__ wtin,    // [E][2H][D] fp8 (pre-transposed)
    const float* __restrict__ bin,  // [E][2H] f32
    const int* __restrict__ ws_idx, const float* __restrict__ ws_w,
    u8* __restrict__ hid)           // [B*2][S][H] fp8
{
  const int nt = blockIdx.x;   // 32 tiles of 64 hid-cols
  const int mt = blockIdx.y;   // 8 s-tiles
  const int z  = blockIdx.z;   // 16 = b*2+slot
  const int b  = z >> 1;
  const int e  = ws_idx[z] & 7;
  const float csc = ws_w[z];

  __shared__ u8 As[128 * 64];   // 8 KB
  __shared__ u8 Bs[128 * 64];   // 8 KB: rows 0-63 value cols, 64-127 gate cols

  const int t = threadIdx.x;
  const int wave = t >> 6, lane = t & 63;
  const int wm = wave >> 1, wn = wave & 1;
  const int lm = lane & 15, lq = lane >> 4;
  const int lrow4 = lane >> 2;                       // staging row within 16-row chunk
  const int kq = ((lane & 3) ^ swz(lrow4)) * 16;     // swizzled 16B-pair fetch offset
  const int fsw = swz(lm);                           // fragment-read row swizzle
  const int p0 = lq >> 1, fb = (lq & 1) * 8;         // frag pair base / byte-in-pair

  const u8* Ab  = xq + (size_t)b * (S_ * D_) + (size_t)mt * 128 * D_;
  const u8* Bvb = wtin + (size_t)e * (2 * H_ * D_) + (size_t)nt * 64 * D_;
  const u8* Bgb = Bvb + (size_t)H_ * D_;

  const f32x4 vz = {0.f, 0.f, 0.f, 0.f};
  f32x4 accv[4][2], accg[4][2];
#pragma unroll
  for (int i = 0; i < 4; ++i)
#pragma unroll
    for (int j = 0; j < 2; ++j) { accv[i][j] = vz; accg[i][j] = vz; }

  for (int kt = 0; kt < D_ / 64; ++kt) {             // 16 k-iters
    const int k0 = kt * 64 + kq;
    gll16(Ab + (size_t)(wave * 16 + lrow4) * D_ + k0, (char*)As + wave * 1024);
    gll16(Ab + (size_t)((wave + 4) * 16 + lrow4) * D_ + k0, (char*)As + (wave + 4) * 1024);
    gll16(Bvb + (size_t)(wave * 16 + lrow4) * D_ + k0, (char*)Bs + wave * 1024);
    gll16(Bgb + (size_t)(wave * 16 + lrow4) * D_ + k0, (char*)Bs + 4096 + wave * 1024);
    __syncthreads();
    ll af[4][2], bvf[2][2], bgf[2][2];
#pragma unroll
    for (int h = 0; h < 2; ++h) {
      const int pw = ((h * 2 + p0) ^ fsw) * 16 + fb;
#pragma unroll
      for (int i = 0; i < 4; ++i)
        af[i][h] = *(const ll*)(As + (wm * 64 + i * 16 + lm) * 64 + pw);
#pragma unroll
      for (int j = 0; j < 2; ++j) {
        bvf[j][h] = *(const ll*)(Bs + (wn * 32 + j * 16 + lm) * 64 + pw);
        bgf[j][h] = *(const ll*)(Bs + (64 + wn * 32 + j * 16 + lm) * 64 + pw);
      }
    }
#pragma unroll
    for (int h = 0; h < 2; ++h)
#pragma unroll
      for (int i = 0; i < 4; ++i)
#pragma unroll
        for (int j = 0; j < 2; ++j) {
          accv[i][j] = __builtin_amdgcn_mfma_f32_16x16x32_fp8_fp8(af[i][h], bvf[j][h], accv[i][j], 0, 0, 0);
          accg[i][j] = __builtin_amdgcn_mfma_f32_16x16x32_fp8_fp8(af[i][h], bgf[j][h], accg[i][j], 0, 0, 0);
        }
    __syncthreads();
  }

  u8* hb = hid + (size_t)z * (S_ * H_);
  const int row0 = mt * 128 + wm * 64;
  const int col0 = nt * 64 + wn * 32;
#pragma unroll
  for (int j = 0; j < 2; ++j) {
    const int col = col0 + j * 16 + lm;
    const float bvx = bin[e * 2 * H_ + col];
    const float bgx = bin[e * 2 * H_ + H_ + col];
#pragma unroll
    for (int i = 0; i < 4; ++i) {
#pragma unroll
      for (int r = 0; r < 4; ++r) {
        const int srow = row0 + i * 16 + lq * 4 + r;
        float v = accv[i][j][r] + bvx;
        float g = accg[i][j][r] + bgx;
        float hv = v * g / (1.f + __expf(-g)) * csc;   // value * silu(gate) * coeff
        hb[(size_t)srow * H_ + col] = f2f8(hv);
      }
    }
  }
}

// ---------------- GEMM2: mixed[b] = sum_slots hidden[b,slot] @ W_out[e] + bias (fp8) ---
__global__ void __launch_bounds__(256, 2) gemm2_kernel(
    const u8* __restrict__ hid,     // [B*2][S][H] fp8 (coeff pre-applied)
    const u8* __restrict__ wtout,   // [E][D][H] fp8 (pre-transposed)
    const float* __restrict__ bout, // [E][D] f32
    const int* __restrict__ ws_idx, const float* __restrict__ ws_w,
    float* __restrict__ out)        // [B][S][D] f32
{
  const int nt = blockIdx.x;  // 8 d-tiles
  const int mt = blockIdx.y;  // 8 s-tiles
  const int b  = blockIdx.z;  // 8

  __shared__ u8 As[128 * 64];
  __shared__ u8 Bs[128 * 64];

  const int t = threadIdx.x;
  const int wave = t >> 6, lane = t & 63;
  const int wm = wave >> 1, wn = wave & 1;
  const int lm = lane & 15, lq = lane >> 4;
  const int lrow4 = lane >> 2;
  const int kq = ((lane & 3) ^ swz(lrow4)) * 16;
  const int fsw = swz(lm);
  const int p0 = lq >> 1, fb = (lq & 1) * 8;

  const f32x4 vz = {0.f, 0.f, 0.f, 0.f};
  f32x4 acc[4][4];
#pragma unroll
  for (int i = 0; i < 4; ++i)
#pragma unroll
    for (int j = 0; j < 4; ++j) acc[i][j] = vz;

  for (int slot = 0; slot < 2; ++slot) {
    const int e = ws_idx[b * 2 + slot] & 7;
    const u8* Ab = hid + ((size_t)(b * 2 + slot) * S_ + mt * 128) * H_;
    const u8* Bb = wtout + ((size_t)e * D_ + nt * 128) * H_;
    for (int kt = 0; kt < H_ / 64; ++kt) {           // 32 k-iters per slot
      const int k0 = kt * 64 + kq;
      gll16(Ab + (size_t)(wave * 16 + lrow4) * H_ + k0, (char*)As + wave * 1024);
      gll16(Ab + (size_t)((wave + 4) * 16 + lrow4) * H_ + k0, (char*)As + (wave + 4) * 1024);
      gll16(Bb + (size_t)(wave * 16 + lrow4) * H_ + k0, (char*)Bs + wave * 1024);
      gll16(Bb + (size_t)((wave + 4) * 16 + lrow4) * H_ + k0, (char*)Bs + (wave + 4) * 1024);
      __syncthreads();
      ll af[4][2], bf[4][2];
#pragma unroll
      for (int h = 0; h < 2; ++h) {
        const int pw = ((h * 2 + p0) ^ fsw) * 16 + fb;
#pragma unroll
        for (int i = 0; i < 4; ++i)
          af[i][h] = *(const ll*)(As + (wm * 64 + i * 16 + lm) * 64 + pw);
#pragma unroll
        for (int j = 0; j < 4; ++j)
          bf[j][h] = *(const ll*)(Bs + (wn * 64 + j * 16 + lm) * 64 + pw);
      }
#pragma unroll
      for (int h = 0; h < 2; ++h)
#pragma unroll
        for (int i = 0; i < 4; ++i)
#pragma unroll
          for (int j = 0; j < 4; ++j)
            acc[i][j] = __builtin_amdgcn_mfma_f32_16x16x32_fp8_fp8(af[i][h], bf[j][h], acc[i][j], 0, 0, 0);
      __syncthreads();
    }
  }

  const int e0 = ws_idx[b * 2] & 7, e1 = ws_idx[b * 2 + 1] & 7;
  const float c0 = ws_w[b * 2], c1 = ws_w[b * 2 + 1];
  float* ob = out + (size_t)b * (S_ * D_);
  const int row0 = mt * 128 + wm * 64;
  const int col0 = nt * 128 + wn * 64;
#pragma unroll
  for (int j = 0; j < 4; ++j) {
    const int col = col0 + j * 16 + lm;
    const float bias = c0 * bout[e0 * D_ + col] + c1 * bout[e1 * D_ + col];
#pragma unroll
    for (int i = 0; i < 4; ++i)
#pragma unroll
      for (int r = 0; r < 4; ++r)
        ob[(size_t)(row0 + i * 16 + lq * 4 + r) * D_ + col] = acc[i][j][r] + bias;
  }
}

extern "C" void kernel_launch(void* const* d_in, const int* in_sizes, int n_in,
                              void* d_out, int out_size, void* d_ws, size_t ws_size,
                              hipStream_t stream) {
  const float* x     = (const float*)d_in[0];
  const float* noise = (const float*)d_in[1];
  const float* rw    = (const float*)d_in[2];
  const float* fiw   = (const float*)d_in[3];
  const float* fib   = (const float*)d_in[4];
  const float* fow   = (const float*)d_in[5];
  const float* fob   = (const float*)d_in[6];
  float* out = (float*)d_out;

  char* ws = (char*)d_ws;
  int*   ws_idx = (int*)ws;                                 // 16 ints
  float* ws_w   = (float*)(ws + 64);                        // 16 floats
  u8* xq    = (u8*)(ws + 256);                              // [B][S][D] fp8 (8 MB)
  u8* wtin  = xq + (size_t)B_ * S_ * D_;                    // [E][2H][D] fp8 (32 MB)
  u8* wtout = wtin + (size_t)E_ * 2 * H_ * D_;              // [E][D][H] fp8 (16 MB)
  u8* hid   = wtout + (size_t)E_ * D_ * H_;                 // [B*2][S][H] fp8 (32 MB)

  float* out_mixed  = out;
  float* out_logits = out + (size_t)B_ * S_ * D_;
  float* out_probs  = out_logits + B_ * E_;
  float* out_idx    = out_probs + B_ * E_;
  float* out_w      = out_idx + B_ * 2;

  router_kernel<<<1, 64, 0, stream>>>(noise, rw, out_logits, out_probs,
                                      out_idx, out_w, ws_idx, ws_w);
  cast_x_kernel<<<(B_ * S_ * D_ / 4) / 256, 256, 0, stream>>>(x, (unsigned int*)xq);
  transpose_cast_kernel<D_, 2 * H_><<<dim3((2 * H_) / 64, D_ / 64, E_), 256, 0, stream>>>(fiw, wtin);
  transpose_cast_kernel<H_, D_><<<dim3(D_ / 64, H_ / 64, E_), 256, 0, stream>>>(fow, wtout);
  gemm1_kernel<<<dim3(32, 8, 16), 256, 0, stream>>>(xq, wtin, fib, ws_idx, ws_w, hid);
  gemm2_kernel<<<dim3(8, 8, 8), 256, 0, stream>>>(hid, wtout, fob, ws_idx, ws_w, out_mixed);
}